// Round 1
// baseline (339.911 us; speedup 1.0000x reference)
//
#include <hip/hip_runtime.h>

// AssociativeScanGateLoop: h_t = f_t*h_{t-1} + i_t*v_t per (b,d) sequence.
// x: (B=4, T=8192, 3*512) fp32.  out: (4, 8192, 512) fp32.
// Two-kernel chunked scan: K1 computes per-chunk affine aggregates (A, KV),
// K2 folds predecessor aggregates into a starting state and recomputes+writes.

#define B_  4
#define T_  8192
#define DH_ 512
#define ROW_ 1536

__device__ __forceinline__ float sigmoid_f(float x) {
    // 1/(1+e^-x): e^-x -> inf for very negative x gives 0 gracefully.
    return 1.0f / (1.0f + __expf(-x));
}

__device__ __forceinline__ float tanh_f(float x) {
    // 1 - 2/(e^{2x}+1): saturates to +/-1 even when __expf overflows to inf.
    return 1.0f - 2.0f / (__expf(2.0f * x) + 1.0f);
}

// K1: per-chunk aggregate of the affine recurrence.
// Aggregate over chunk: state' = (A,KV) with h_out = A*h_in + KV.
// Sequential update per step t: A = f_t*A; KV = f_t*KV + i_t*v_t.
__global__ void k_partials(const float* __restrict__ x,
                           float* __restrict__ agg_a,
                           float* __restrict__ agg_kv,
                           int C, int Tc) {
    const int c = blockIdx.x;
    const int b = blockIdx.y;
    const int d = threadIdx.x;           // 512 threads, one channel each
    const float* xb = x + (size_t)b * T_ * ROW_;
    const int t0 = c * Tc;

    float A = 1.0f, KV = 0.0f;
#pragma unroll 4
    for (int i = 0; i < Tc; ++i) {
        const size_t off = (size_t)(t0 + i) * ROW_ + d;
        const float xi = xb[off];          // pre-tanh input
        const float gi = xb[off + DH_];    // pre-sigmoid input gate
        const float s  = sigmoid_f(gi);    // input gate
        const float f  = 1.0f - s;         // forget gate
        const float iv = tanh_f(xi) * s;
        A  = f * A;
        KV = f * KV + iv;
    }
    const size_t idx = ((size_t)b * C + c) * DH_ + d;
    agg_a[idx]  = A;
    agg_kv[idx] = KV;
}

// K2: fold predecessor aggregates (exclusive prefix, h_init = 0 so only KV
// survives), then recompute the chunk with the carried state and write output.
__global__ void k_apply(const float* __restrict__ x,
                        const float* __restrict__ agg_a,
                        const float* __restrict__ agg_kv,
                        float* __restrict__ out,
                        int C, int Tc) {
    const int c = blockIdx.x;
    const int b = blockIdx.y;
    const int d = threadIdx.x;

    // Exclusive prefix over chunks [0, c): h0 = fold of affine maps on h=0.
    float h = 0.0f;
    for (int cc = 0; cc < c; ++cc) {
        const size_t idx = ((size_t)b * C + cc) * DH_ + d;
        h = agg_a[idx] * h + agg_kv[idx];
    }

    const float* xb = x + (size_t)b * T_ * ROW_;
    float* ob = out + (size_t)b * T_ * DH_;
    const int t0 = c * Tc;

#pragma unroll 4
    for (int i = 0; i < Tc; ++i) {
        const size_t off = (size_t)(t0 + i) * ROW_ + d;
        const float xi = xb[off];
        const float gi = xb[off + DH_];
        const float go = xb[off + 2 * DH_];
        const float s  = sigmoid_f(gi);
        const float f  = 1.0f - s;
        const float iv = tanh_f(xi) * s;
        h = f * h + iv;
        ob[(size_t)(t0 + i) * DH_ + d] = tanh_f(h) * sigmoid_f(go);
    }
}

extern "C" void kernel_launch(void* const* d_in, const int* in_sizes, int n_in,
                              void* d_out, int out_size, void* d_ws, size_t ws_size,
                              hipStream_t stream) {
    const float* x = (const float*)d_in[0];
    float* out = (float*)d_out;

    // Pick chunk count C (power of two dividing T) to fit aggregates in d_ws.
    int C = 128;
    while (C > 1 && (size_t)B_ * C * DH_ * 2 * sizeof(float) > ws_size) C >>= 1;
    const int Tc = T_ / C;

    float* agg_a  = (float*)d_ws;
    float* agg_kv = agg_a + (size_t)B_ * C * DH_;

    dim3 grid(C, B_);
    dim3 block(DH_);
    hipLaunchKernelGGL(k_partials, grid, block, 0, stream, x, agg_a, agg_kv, C, Tc);
    hipLaunchKernelGGL(k_apply,    grid, block, 0, stream, x, agg_a, agg_kv, out, C, Tc);
}